// Round 8
// baseline (137.730 us; speedup 1.0000x reference)
//
#include <hip/hip_runtime.h>
#include <hip/hip_cooperative_groups.h>
#include <stdint.h>

namespace cg = cooperative_groups;

typedef __bf16 bf16x8 __attribute__((ext_vector_type(8)));
typedef __bf16 bf16x4 __attribute__((ext_vector_type(4)));
typedef float  f32x16 __attribute__((ext_vector_type(16)));

constexpr int kB = 16;
constexpr int kN = 1024;

struct bfhl { __bf16 h, l; };
__device__ __forceinline__ bfhl hilo(float v) {
    bfhl r;
    r.h = (__bf16)v;
    r.l = (__bf16)(v - (float)r.h);
    return r;
}

// m-offset ordering of P fragments: P0[j] holds row (j<4 ? j+4h : j+4+4h),
// P1 the same +16. V fragments are written in the identical order.
__device__ __forceinline__ int moff(int f, int h, int j) {
    return 16 * f + ((j < 4) ? (4 * h + j) : (4 * h + j + 4));
}

// ---------------------------------------------------------------------------
// Single cooperative kernel, grid 512 (= b*32 + ntile), 256 threads, 2 blk/CU.
// Phase 0: prep  emb->esf frags, x->vtf1 frags (+LDS x tile), Wp->wq, stock->LDS
// Phase 1: apply1 (V=vtf1): y1 -> yb (LDS, persists) + vtf2 frags (global)
// Phase 2: apply2 (V=vtf2) + fused final GEMM -> out
// Fragment layouts (bf16, lane = h*32 + (l&31), 8 elems = 16B/lane):
//  esf [b][kt(32)][pl(2)][lane][8] : E_pl[kt*32+(l&31)][8h+j]
//  vtf [b][mt(32)][f(2)][lane][8]  : V[d=(l&31)][mt*32+moff(f,h,j)]
//  wq  [e][ks(6)][o*16+h*8+j]      : W_hi[16ks+8h+j][o]
// ---------------------------------------------------------------------------
__global__ __launch_bounds__(256, 2) void dygcn_fused(
    const float* __restrict__ emb, const float* __restrict__ x,
    const float* __restrict__ Wp, const float* __restrict__ stock,
    const float* __restrict__ bias,
    __bf16* __restrict__ esf, __bf16* __restrict__ vtf1,
    __bf16* __restrict__ vtf2, __bf16* __restrict__ wq,
    float* __restrict__ out)
{
    __shared__ alignas(16) char smem[28672];
    float*  ps  = (float*)smem;             // 4224 f32 (phase0: x-tile ls)
    float*  Ls  = (float*)(smem + 16896);   // 128 f32
    float*  yb  = (float*)(smem + 17408);   // 32*36 f32 (y1, persists ph1->ph2)
    __bf16* xg2 = (__bf16*)(smem + 22016);  // [2][32][36] bf16 (2*y2-x)
    float*  s_s = (float*)(smem + 26624);   // 32*16 f32 (stock)

    cg::grid_group grid = cg::this_grid();

    const int tid = threadIdx.x;
    const int bid = blockIdx.x;
    const int w = tid >> 6, l = tid & 63;
    const int q = l & 31, h = l >> 5;
    const int b = bid >> 5, nt = bid & 31, q0 = nt << 5;

    const __bf16* esfB = esf + (size_t)b * 32768;

    // ================= phase 0: prep =================
    {
        float* ls = ps;   // alias (free until phase-1 merge)
        {   // x tile (32 rows x 32) -> LDS
            int row = tid >> 3, q8 = tid & 7;
            float4 v = *(const float4*)(x + (size_t)(b * kN + q0 + row) * 32 + q8 * 4);
            *(float4*)(&ls[row * 36 + q8 * 4]) = v;
        }
        {   // stock tile -> s_s (persists to phase 2)
            int r = tid >> 3, e2 = (tid & 7) * 2;
            *(float2*)(s_s + r * 16 + e2) =
                *(const float2*)(stock + (size_t)(b * kN + q0 + r) * 16 + e2);
        }
        if (tid < 128) {   // emb -> esf fragments (own kt = nt)
            int r = tid >> 2, seg = tid & 3;
            float4 v = *(const float4*)(emb + (size_t)(b * kN + q0 + r) * 16 + seg * 4);
            float f[4] = {v.x, v.y, v.z, v.w};
            bf16x4 hi, lo;
            #pragma unroll
            for (int i = 0; i < 4; ++i) { bfhl t = hilo(f[i]); hi[i] = t.h; lo[i] = t.l; }
            int lane = ((seg >> 1) << 5) + r;
            int j0 = (seg & 1) << 2;
            __bf16* base = esf + ((size_t)(b * 32 + nt) * 2) * 512 + lane * 8 + j0;
            *(bf16x4*)base         = hi;
            *(bf16x4*)(base + 512) = lo;
        }
        if (bid < 48 && tid < 128) {   // Wp -> wq (hi plane), 128 entries/block
            int idx = bid * 128 + tid;          // (e, ks, o, h)
            int e = idx / 384, rem = idx - e * 384;
            int ks = rem / 64, r2 = rem - ks * 64;
            int o = r2 >> 1, hh = r2 & 1;
            int ki0 = ks * 16 + hh * 8;
            bf16x8 hi;
            #pragma unroll
            for (int j = 0; j < 8; ++j)
                hi[j] = (__bf16)Wp[(size_t)e * 3072 + (size_t)(ki0 + j) * 32 + o];
            *(bf16x8*)(wq + (size_t)(e * 6 + ks) * 512 + o * 16 + hh * 8) = hi;
        }
        __syncthreads();
        if (tid < 128) {   // vtf1 fragments from LDS x tile (own mt = nt)
            int fr = tid >> 6, l2 = tid & 63;
            int d = l2 & 31, h2 = l2 >> 5;
            bf16x8 ov;
            #pragma unroll
            for (int j = 0; j < 8; ++j)
                ov[j] = (__bf16)ls[moff(fr, h2, j) * 36 + d];
            *(bf16x8*)(vtf1 + ((size_t)(b * 32 + nt) * 2 + fr) * 512 + l2 * 8) = ov;
        }
    }
    grid.sync();

    // ================= phase 1: apply stage 1 (V = x) =================
    {
        const __bf16* vtfB = vtf1 + (size_t)b * 32768;
        bf16x8 bhi = *(const bf16x8*)(esfB + ((size_t)nt * 2) * 512 + l * 8);
        bf16x8 blo = *(const bf16x8*)(esfB + ((size_t)nt * 2 + 1) * 512 + l * 8);

        f32x16 acc = {};
        float Lp = 0.f;
        #pragma unroll 2
        for (int it = 0; it < 8; ++it) {
            const int kt = it * 4 + w;
            bf16x8 ahi = *(const bf16x8*)(esfB + ((size_t)kt * 2) * 512 + l * 8);
            bf16x8 alo = *(const bf16x8*)(esfB + ((size_t)kt * 2 + 1) * 512 + l * 8);
            bf16x8 A0  = *(const bf16x8*)(vtfB + ((size_t)kt * 2) * 512 + l * 8);
            bf16x8 A1  = *(const bf16x8*)(vtfB + ((size_t)kt * 2 + 1) * 512 + l * 8);

            f32x16 S = {};
            S = __builtin_amdgcn_mfma_f32_32x32x16_bf16(ahi, bhi, S, 0, 0, 0);
            S = __builtin_amdgcn_mfma_f32_32x32x16_bf16(ahi, blo, S, 0, 0, 0);
            S = __builtin_amdgcn_mfma_f32_32x32x16_bf16(alo, bhi, S, 0, 0, 0);

            float p[16];
            #pragma unroll
            for (int r = 0; r < 16; ++r) {
                p[r] = __expf(fmaxf(S[r], 0.f));
                Lp += p[r];
            }
            bf16x8 P0, P1;
            #pragma unroll
            for (int j = 0; j < 8; ++j) { P0[j] = (__bf16)p[j]; P1[j] = (__bf16)p[8 + j]; }

            acc = __builtin_amdgcn_mfma_f32_32x32x16_bf16(A0, P0, acc, 0, 0, 0);
            acc = __builtin_amdgcn_mfma_f32_32x32x16_bf16(A1, P1, acc, 0, 0, 0);
        }

        Lp += __shfl_xor(Lp, 32);
        #pragma unroll
        for (int r = 0; r < 16; ++r) {
            int d = (r & 3) + 8 * (r >> 2) + 4 * h;
            ps[w * 1056 + d * 33 + q] = acc[r];
        }
        if (l < 32) Ls[w * 32 + l] = Lp;
        __syncthreads();

        const int qq = tid >> 3, dg = tid & 7;
        const float iL = 1.f / (Ls[qq] + Ls[32 + qq] + Ls[64 + qq] + Ls[96 + qq]);
        #pragma unroll
        for (int i = 0; i < 4; ++i) {
            int d = dg * 4 + i;
            yb[qq * 36 + d] = (ps[d * 33 + qq] + ps[1056 + d * 33 + qq] +
                               ps[2112 + d * 33 + qq] + ps[3168 + d * 33 + qq]) * iL;
        }
        __syncthreads();
        if (tid < 128) {   // vtf2 fragments from yb (own mt = nt)
            int fr = tid >> 6, l2 = tid & 63;
            int d = l2 & 31, h2 = l2 >> 5;
            bf16x8 ov;
            #pragma unroll
            for (int j = 0; j < 8; ++j)
                ov[j] = (__bf16)yb[moff(fr, h2, j) * 36 + d];
            *(bf16x8*)(vtf2 + ((size_t)(b * 32 + nt) * 2 + fr) * 512 + l2 * 8) = ov;
        }
    }
    grid.sync();

    // ================= phase 2: apply stage 2 + fused final =================
    {
        const __bf16* vtfB = vtf2 + (size_t)b * 32768;
        bf16x8 bhi = *(const bf16x8*)(esfB + ((size_t)nt * 2) * 512 + l * 8);
        bf16x8 blo = *(const bf16x8*)(esfB + ((size_t)nt * 2 + 1) * 512 + l * 8);

        f32x16 acc = {};
        float Lp = 0.f;
        #pragma unroll 2
        for (int it = 0; it < 8; ++it) {
            const int kt = it * 4 + w;
            bf16x8 ahi = *(const bf16x8*)(esfB + ((size_t)kt * 2) * 512 + l * 8);
            bf16x8 alo = *(const bf16x8*)(esfB + ((size_t)kt * 2 + 1) * 512 + l * 8);
            bf16x8 A0  = *(const bf16x8*)(vtfB + ((size_t)kt * 2) * 512 + l * 8);
            bf16x8 A1  = *(const bf16x8*)(vtfB + ((size_t)kt * 2 + 1) * 512 + l * 8);

            f32x16 S = {};
            S = __builtin_amdgcn_mfma_f32_32x32x16_bf16(ahi, bhi, S, 0, 0, 0);
            S = __builtin_amdgcn_mfma_f32_32x32x16_bf16(ahi, blo, S, 0, 0, 0);
            S = __builtin_amdgcn_mfma_f32_32x32x16_bf16(alo, bhi, S, 0, 0, 0);

            float p[16];
            #pragma unroll
            for (int r = 0; r < 16; ++r) {
                p[r] = __expf(fmaxf(S[r], 0.f));
                Lp += p[r];
            }
            bf16x8 P0, P1;
            #pragma unroll
            for (int j = 0; j < 8; ++j) { P0[j] = (__bf16)p[j]; P1[j] = (__bf16)p[8 + j]; }

            acc = __builtin_amdgcn_mfma_f32_32x32x16_bf16(A0, P0, acc, 0, 0, 0);
            acc = __builtin_amdgcn_mfma_f32_32x32x16_bf16(A1, P1, acc, 0, 0, 0);
        }

        Lp += __shfl_xor(Lp, 32);
        #pragma unroll
        for (int r = 0; r < 16; ++r) {
            int d = (r & 3) + 8 * (r >> 2) + 4 * h;
            ps[w * 1056 + d * 33 + q] = acc[r];
        }
        if (l < 32) Ls[w * 32 + l] = Lp;
        __syncthreads();

        const int qq = tid >> 3, dg = tid & 7;
        {
            const float iL = 1.f / (Ls[qq] + Ls[32 + qq] + Ls[64 + qq] + Ls[96 + qq]);
            float4 xv = *(const float4*)(x + (size_t)(b * kN + q0 + qq) * 32 + dg * 4);
            float xa[4] = {xv.x, xv.y, xv.z, xv.w};
            bf16x4 hi, lo;
            #pragma unroll
            for (int i = 0; i < 4; ++i) {
                int d = dg * 4 + i;
                float y2v = (ps[d * 33 + qq] + ps[1056 + d * 33 + qq] +
                             ps[2112 + d * 33 + qq] + ps[3168 + d * 33 + qq]) * iL;
                bfhl t = hilo(2.f * y2v - xa[i]);
                hi[i] = t.h; lo[i] = t.l;
            }
            *(bf16x4*)(xg2 + qq * 36 + dg * 4)        = hi;
            *(bf16x4*)(xg2 + 1152 + qq * 36 + dg * 4) = lo;
        }
        __syncthreads();

        // ---- fused final GEMM ----
        f32x16 acc2[4] = {};
        const int e0 = w * 4;
        const int o = q;   // A-side node index == B/D-side o index

        #pragma unroll
        for (int ks = 0; ks < 6; ++ks) {
            bf16x8 Ah, Al;
            if (ks < 2) {          // XG k 0..31 = x, straight from global
                const float* rp = x + (size_t)(b * kN + q0 + q) * 32 + ks * 16 + 8 * h;
                float4 u0 = *(const float4*)rp;
                float4 u1 = *(const float4*)(rp + 4);
                float u[8] = {u0.x, u0.y, u0.z, u0.w, u1.x, u1.y, u1.z, u1.w};
                #pragma unroll
                for (int j = 0; j < 8; ++j) { bfhl t = hilo(u[j]); Ah[j] = t.h; Al[j] = t.l; }
            } else if (ks < 4) {   // XG k 32..63 = y1, from yb (LDS, fp32)
                const float* rp = yb + q * 36 + (ks - 2) * 16 + 8 * h;
                float4 u0 = *(const float4*)rp;
                float4 u1 = *(const float4*)(rp + 4);
                float u[8] = {u0.x, u0.y, u0.z, u0.w, u1.x, u1.y, u1.z, u1.w};
                #pragma unroll
                for (int j = 0; j < 8; ++j) { bfhl t = hilo(u[j]); Ah[j] = t.h; Al[j] = t.l; }
            } else {               // XG k 64..95 = 2*y2-x, from xg2 (bf16)
                const int base = o * 36 + (ks - 4) * 16 + 8 * h;
                bf16x4 a0 = *(const bf16x4*)(xg2 + base);
                bf16x4 a1 = *(const bf16x4*)(xg2 + base + 4);
                bf16x4 b0 = *(const bf16x4*)(xg2 + 1152 + base);
                bf16x4 b1 = *(const bf16x4*)(xg2 + 1152 + base + 4);
                #pragma unroll
                for (int j = 0; j < 4; ++j) {
                    Ah[j] = a0[j]; Ah[4 + j] = a1[j];
                    Al[j] = b0[j]; Al[4 + j] = b1[j];
                }
            }
            #pragma unroll
            for (int ei = 0; ei < 4; ++ei) {
                bf16x8 Bh = *(const bf16x8*)(wq + (size_t)((e0 + ei) * 6 + ks) * 512 + o * 16 + h * 8);
                acc2[ei] = __builtin_amdgcn_mfma_f32_32x32x16_bf16(Ah, Bh, acc2[ei], 0, 0, 0);
                acc2[ei] = __builtin_amdgcn_mfma_f32_32x32x16_bf16(Al, Bh, acc2[ei], 0, 0, 0);
            }
        }

        float pr[16];
        #pragma unroll
        for (int r = 0; r < 16; ++r) pr[r] = 0.f;
        #pragma unroll
        for (int ei = 0; ei < 4; ++ei) {
            const int eg = e0 + ei;
            const float bv = bias[eg * 32 + o];
            #pragma unroll
            for (int r = 0; r < 16; ++r) {
                int node = (r & 3) + 8 * (r >> 2) + 4 * h;
                pr[r] += s_s[node * 16 + eg] * (acc2[ei][r] + bv);
            }
        }
        #pragma unroll
        for (int r = 0; r < 16; ++r) {
            int node = (r & 3) + 8 * (r >> 2) + 4 * h;
            ps[w * 1056 + node * 33 + o] = pr[r];
        }
        __syncthreads();
        {
            const int node = tid >> 3, og = (tid & 7) * 4;
            float4 s;
            #pragma unroll
            for (int i = 0; i < 4; ++i) {
                int c = node * 33 + og + i;
                ((float*)&s)[i] = ps[c] + ps[1056 + c] + ps[2112 + c] + ps[3168 + c];
            }
            *(float4*)(out + (size_t)(b * kN + q0 + node) * 32 + og) = s;
        }
    }
}

extern "C" void kernel_launch(void* const* d_in, const int* in_sizes, int n_in,
                              void* d_out, int out_size, void* d_ws, size_t ws_size,
                              hipStream_t stream) {
    const float* x     = (const float*)d_in[0];
    const float* aemb  = (const float*)d_in[1];
    const float* stock = (const float*)d_in[2];
    const float* Wp    = (const float*)d_in[3];
    const float* bias  = (const float*)d_in[4];
    float* out = (float*)d_out;

    __bf16* wsb  = (__bf16*)d_ws;
    __bf16* esf  = wsb;               // 524288 bf16
    __bf16* vtf1 = wsb + 524288;      // 524288 bf16
    __bf16* vtf2 = wsb + 1048576;     // 524288 bf16
    __bf16* wq   = wsb + 1572864;     // 49152 bf16

    void* args[] = {(void*)&aemb, (void*)&x, (void*)&Wp, (void*)&stock,
                    (void*)&bias, (void*)&esf, (void*)&vtf1, (void*)&vtf2,
                    (void*)&wq, (void*)&out};
    hipLaunchCooperativeKernel((const void*)dygcn_fused, dim3(512), dim3(256),
                               args, 0, stream);
}

// Round 9
// 31.258 us; speedup vs baseline: 4.4062x; 4.4062x over previous
//
#include <hip/hip_runtime.h>
#include <stdint.h>

typedef __bf16 bf16x8 __attribute__((ext_vector_type(8)));
typedef __bf16 bf16x4 __attribute__((ext_vector_type(4)));
typedef float  f32x16 __attribute__((ext_vector_type(16)));

constexpr int kB = 16;
constexpr int kN = 1024;
constexpr float kLog2e = 1.44269504088896340736f;

struct bfhl { __bf16 h, l; };
__device__ __forceinline__ bfhl hilo(float v) {
    bfhl r;
    r.h = (__bf16)v;
    r.l = (__bf16)(v - (float)r.h);
    return r;
}

// m-offset ordering of P fragments: P0[j] holds row (j<4 ? j+4h : j+4+4h),
// P1 the same +16. V fragments are written in the identical order.
__device__ __forceinline__ int moff(int f, int h, int j) {
    return 16 * f + ((j < 4) ? (4 * h + j) : (4 * h + j + 4));
}

// ---------------------------------------------------------------------------
// Fragment layouts (bf16, lane = h*32 + (l&31), 8 elems = 16B/lane):
//  esf [b][kt(32)][pl(2)][lane][8] : E_pl[kt*32+(l&31)][8h+j]
//  esq same but E scaled by log2e (Q-side operand; exp2 domain)
//  vtf [b][mt(32)][f(2)][lane][8]  : V[d=(l&31)][mt*32+moff(f,h,j)]
//  y1f [gnt(512)][ks(2)][pl(2)][lane][8] : y1_pl[node=(l&31)][32+16ks+8h+j]
//  wq  [e][ks(6)][o*16+h*8+j]      : W_hi[16ks+8h+j][o]
// ---------------------------------------------------------------------------

__global__ __launch_bounds__(256) void prep(
    const float* __restrict__ emb, const float* __restrict__ x,
    const float* __restrict__ Wp,
    __bf16* __restrict__ esf, __bf16* __restrict__ esq,
    __bf16* __restrict__ vtf1, __bf16* __restrict__ wq)
{
    __shared__ float ls[64 * 36];
    const int tid = threadIdx.x;
    const int bid = blockIdx.x;

    if (bid < 256) {
        // emb -> esf + esq fragments. block = batch b, 64 rows.
        const int b = bid >> 4, rg = (bid & 15) << 6;
        const int r = tid >> 2, seg = tid & 3;
        float4 v = *(const float4*)(emb + ((size_t)(b * kN + rg + r) * 16 + seg * 4));
        float f[4] = {v.x, v.y, v.z, v.w};
        bf16x4 hi, lo, qhi, qlo;
        #pragma unroll
        for (int i = 0; i < 4; ++i) {
            bfhl t = hilo(f[i]);           hi[i] = t.h;  lo[i] = t.l;
            bfhl s = hilo(f[i] * kLog2e);  qhi[i] = s.h; qlo[i] = s.l;
        }
        const int kt = ((bid & 15) << 1) + (r >> 5);
        const int lane = ((seg >> 1) << 5) + (r & 31);
        const int j0 = (seg & 1) << 2;
        const size_t off = ((size_t)(b * 32 + kt) * 2) * 512 + lane * 8 + j0;
        *(bf16x4*)(esf + off)       = hi;
        *(bf16x4*)(esf + off + 512) = lo;
        *(bf16x4*)(esq + off)       = qhi;
        *(bf16x4*)(esq + off + 512) = qlo;
    } else if (bid < 512) {
        // x -> vtf1 fragments. block = batch b, 64 rows (2 m-tiles).
        const int bb = bid - 256;
        const int b = bb >> 4, n0 = (bb & 15) << 6;
        const float* sB = x + ((size_t)b * kN + n0) * 32;
        #pragma unroll
        for (int it = 0; it < 2; ++it) {
            int f = it * 256 + tid;
            int row = f >> 3, q8 = f & 7;
            float4 v = *(const float4*)(sB + (size_t)row * 32 + q8 * 4);
            *(float4*)(&ls[row * 36 + q8 * 4]) = v;
        }
        __syncthreads();
        {
            const int mt = tid >> 7, fr = (tid >> 6) & 1, l = tid & 63;
            const int d = l & 31, h = l >> 5;
            bf16x8 ov;
            #pragma unroll
            for (int j = 0; j < 8; ++j)
                ov[j] = (__bf16)ls[(mt * 32 + moff(fr, h, j)) * 36 + d];
            *(bf16x8*)(vtf1 + ((size_t)(b * 32 + (n0 >> 5) + mt) * 2 + fr) * 512 + l * 8) = ov;
        }
    } else {
        int idx = (bid - 512) * 256 + tid;   // (e, ks, o, h)
        if (idx < 6144) {
            int e = idx / 384, rem = idx - e * 384;
            int ks = rem / 64, r2 = rem - ks * 64;
            int o = r2 >> 1, hh = r2 & 1;
            int ki0 = ks * 16 + hh * 8;
            bf16x8 hi;
            #pragma unroll
            for (int j = 0; j < 8; ++j)
                hi[j] = (__bf16)Wp[(size_t)e * 3072 + (size_t)(ki0 + j) * 32 + o];
            *(bf16x8*)(wq + (size_t)(e * 6 + ks) * 512 + o * 16 + hh * 8) = hi;
        }
    }
}

// ---------------------------------------------------------------------------
// apply_mfma<STAGE>: softmax_row(relu(E E^T)) @ V via MFMA; 2 Q-tiles/block.
// grid 256 (XCD-swizzled: whole batch on one XCD -> L2-local re-reads),
// 512 threads (8 waves; wave w handles kt = it*8+w, both Q-tiles).
// STAGE 1: V=vtf1(x); epilogue -> vtf2 frags + y1f frags.
// STAGE 2: V=vtf2(y1); epilogue = fused final GEMM -> out.
// ---------------------------------------------------------------------------
template<int STAGE>
__global__ __launch_bounds__(512, 2) void apply_mfma(
    const __bf16* __restrict__ esf, const __bf16* __restrict__ esq,
    const __bf16* __restrict__ vtin,
    const float*  __restrict__ x,
    __bf16* __restrict__ vtout, __bf16* __restrict__ y1f,
    const __bf16* __restrict__ wq,
    const float*  __restrict__ stock, const float* __restrict__ bias,
    float* __restrict__ out)
{
    __shared__ alignas(16) char smem[57344];
    float*  ps  = (float*)smem;             // 8448 f32
    float*  Ls  = (float*)(smem + 33792);   // 256 f32
    float*  yb0 = (float*)(smem + 34816);   // 32*36 f32
    float*  yb1 = (float*)(smem + 39424);   // 32*36 f32
    __bf16* xg2 = (__bf16*)(smem + 44032);  // [2][64][36] bf16 (stage2)
    float*  s_s = (float*)(smem + 53248);   // 64*16 f32 (stage2)

    const int tid = threadIdx.x;
    const int w = tid >> 6, l = tid & 63;
    const int q = l & 31, h = l >> 5;
    const int sw = ((blockIdx.x & 7) << 5) + (blockIdx.x >> 3);  // XCD swizzle
    const int b = sw >> 4, tg = sw & 15;
    const int q0 = tg << 6;
    const int nt0 = tg << 1;

    const __bf16* esfB = esf + (size_t)b * 32768;
    const __bf16* esqB = esq + (size_t)b * 32768;
    const __bf16* vtfB = vtin + (size_t)b * 32768;

    if (STAGE == 2) {   // stage stock (read after first merge sync)
        int r = tid >> 3, e2 = (tid & 7) * 2;
        *(float2*)(s_s + r * 16 + e2) =
            *(const float2*)(stock + (size_t)(b * kN + q0 + r) * 16 + e2);
    }

    // Q-side B-fragments for both tiles (log2e-scaled)
    bf16x8 bhi0 = *(const bf16x8*)(esqB + ((size_t)nt0 * 2) * 512 + l * 8);
    bf16x8 blo0 = *(const bf16x8*)(esqB + ((size_t)nt0 * 2 + 1) * 512 + l * 8);
    bf16x8 bhi1 = *(const bf16x8*)(esqB + ((size_t)(nt0 + 1) * 2) * 512 + l * 8);
    bf16x8 blo1 = *(const bf16x8*)(esqB + ((size_t)(nt0 + 1) * 2 + 1) * 512 + l * 8);

    f32x16 acc0 = {}, acc1 = {};
    float Lp0 = 0.f, Lp1 = 0.f;

    #pragma unroll
    for (int it = 0; it < 4; ++it) {
        const int kt = it * 8 + w;
        bf16x8 ahi = *(const bf16x8*)(esfB + ((size_t)kt * 2) * 512 + l * 8);
        bf16x8 alo = *(const bf16x8*)(esfB + ((size_t)kt * 2 + 1) * 512 + l * 8);
        bf16x8 A0  = *(const bf16x8*)(vtfB + ((size_t)kt * 2) * 512 + l * 8);
        bf16x8 A1  = *(const bf16x8*)(vtfB + ((size_t)kt * 2 + 1) * 512 + l * 8);

        f32x16 S0 = {}, S1 = {};
        S0 = __builtin_amdgcn_mfma_f32_32x32x16_bf16(ahi, bhi0, S0, 0, 0, 0);
        S0 = __builtin_amdgcn_mfma_f32_32x32x16_bf16(ahi, blo0, S0, 0, 0, 0);
        S0 = __builtin_amdgcn_mfma_f32_32x32x16_bf16(alo, bhi0, S0, 0, 0, 0);
        S1 = __builtin_amdgcn_mfma_f32_32x32x16_bf16(ahi, bhi1, S1, 0, 0, 0);
        S1 = __builtin_amdgcn_mfma_f32_32x32x16_bf16(ahi, blo1, S1, 0, 0, 0);
        S1 = __builtin_amdgcn_mfma_f32_32x32x16_bf16(alo, bhi1, S1, 0, 0, 0);

        float p0[16], p1[16];
        #pragma unroll
        for (int r = 0; r < 16; ++r) {
            p0[r] = exp2f(fmaxf(S0[r], 0.f));  Lp0 += p0[r];
            p1[r] = exp2f(fmaxf(S1[r], 0.f));  Lp1 += p1[r];
        }
        bf16x8 P00, P01, P10, P11;
        #pragma unroll
        for (int j = 0; j < 8; ++j) {
            P00[j] = (__bf16)p0[j]; P01[j] = (__bf16)p0[8 + j];
            P10[j] = (__bf16)p1[j]; P11[j] = (__bf16)p1[8 + j];
        }
        acc0 = __builtin_amdgcn_mfma_f32_32x32x16_bf16(A0, P00, acc0, 0, 0, 0);
        acc0 = __builtin_amdgcn_mfma_f32_32x32x16_bf16(A1, P01, acc0, 0, 0, 0);
        acc1 = __builtin_amdgcn_mfma_f32_32x32x16_bf16(A0, P10, acc1, 0, 0, 0);
        acc1 = __builtin_amdgcn_mfma_f32_32x32x16_bf16(A1, P11, acc1, 0, 0, 0);
    }

    // ---- tile 0 merge (8-wave) ----
    Lp0 += __shfl_xor(Lp0, 32);
    #pragma unroll
    for (int r = 0; r < 16; ++r) {
        int d = (r & 3) + 8 * (r >> 2) + 4 * h;
        ps[w * 1056 + d * 33 + q] = acc0[r];
    }
    if (l < 32) Ls[w * 32 + l] = Lp0;
    __syncthreads();
    {
        const int qq = tid >> 4, dgi = tid & 15;
        float Lsum = 0.f;
        #pragma unroll
        for (int k = 0; k < 8; ++k) Lsum += Ls[k * 32 + qq];
        const float iL = 1.f / Lsum;
        #pragma unroll
        for (int i = 0; i < 2; ++i) {
            int d = dgi * 2 + i;
            float s = 0.f;
            #pragma unroll
            for (int k = 0; k < 8; ++k) s += ps[k * 1056 + d * 33 + qq];
            yb0[qq * 36 + d] = s * iL;
        }
    }
    __syncthreads();
    // ---- tile 1 merge ----
    Lp1 += __shfl_xor(Lp1, 32);
    #pragma unroll
    for (int r = 0; r < 16; ++r) {
        int d = (r & 3) + 8 * (r >> 2) + 4 * h;
        ps[w * 1056 + d * 33 + q] = acc1[r];
    }
    if (l < 32) Ls[w * 32 + l] = Lp1;
    __syncthreads();
    {
        const int qq = tid >> 4, dgi = tid & 15;
        float Lsum = 0.f;
        #pragma unroll
        for (int k = 0; k < 8; ++k) Lsum += Ls[k * 32 + qq];
        const float iL = 1.f / Lsum;
        #pragma unroll
        for (int i = 0; i < 2; ++i) {
            int d = dgi * 2 + i;
            float s = 0.f;
            #pragma unroll
            for (int k = 0; k < 8; ++k) s += ps[k * 1056 + d * 33 + qq];
            yb1[qq * 36 + d] = s * iL;
        }
    }
    __syncthreads();

    if (STAGE == 1) {
        if (tid < 256) {   // vtf2 fragments (both tiles)
            int t = tid >> 7, fr = (tid >> 6) & 1, l2 = tid & 63;
            int d = l2 & 31, h2 = l2 >> 5;
            const float* yb = t ? yb1 : yb0;
            bf16x8 ov;
            #pragma unroll
            for (int j = 0; j < 8; ++j)
                ov[j] = (__bf16)yb[moff(fr, h2, j) * 36 + d];
            *(bf16x8*)(vtout + ((size_t)(b * 32 + nt0 + t) * 2 + fr) * 512 + l2 * 8) = ov;
        }
        {   // y1f fragments (both tiles)
            int t = tid >> 8, rest = tid & 255;
            int ks2 = rest >> 7, pl = (rest >> 6) & 1, l2 = rest & 63;
            int node = l2 & 31, h2 = l2 >> 5;
            const float* yb = t ? yb1 : yb0;
            const float* rp = yb + node * 36 + ks2 * 16 + 8 * h2;
            bf16x8 ov;
            #pragma unroll
            for (int j = 0; j < 8; ++j) {
                bfhl tt = hilo(rp[j]);
                ov[j] = pl ? tt.l : tt.h;
            }
            *(bf16x8*)(y1f + (((size_t)(b * 32 + nt0 + t) * 2 + ks2) * 2 + pl) * 512 + l2 * 8) = ov;
        }
    } else {
        // ---- fused final: xg2 = 2*y2 - x, then out ----
        {
            int node = tid >> 3, dg = tid & 7;
            int t = node >> 5, nl = node & 31;
            const float* yb = t ? yb1 : yb0;
            float4 xv = *(const float4*)(x + (size_t)(b * kN + q0 + node) * 32 + dg * 4);
            float xa[4] = {xv.x, xv.y, xv.z, xv.w};
            bf16x4 hi, lo;
            #pragma unroll
            for (int i = 0; i < 4; ++i) {
                float y2v = yb[nl * 36 + dg * 4 + i];
                bfhl tt = hilo(2.f * y2v - xa[i]);
                hi[i] = tt.h; lo[i] = tt.l;
            }
            *(bf16x4*)(xg2 + node * 36 + dg * 4)        = hi;
            *(bf16x4*)(xg2 + 2304 + node * 36 + dg * 4) = lo;
        }
        __syncthreads();

        f32x16 acc2[4] = {};
        const int t = w >> 2;
        const int e0 = (w & 3) * 4;
        const int o = q;
        const int gnt = b * 32 + nt0 + t;

        #pragma unroll
        for (int ks = 0; ks < 6; ++ks) {
            bf16x8 Ah, Al;
            if (ks < 2) {          // XG k 0..31 = x, from global
                const float* rp = x + (size_t)(b * kN + q0 + t * 32 + q) * 32 + ks * 16 + 8 * h;
                float4 u0 = *(const float4*)rp;
                float4 u1 = *(const float4*)(rp + 4);
                float u[8] = {u0.x, u0.y, u0.z, u0.w, u1.x, u1.y, u1.z, u1.w};
                #pragma unroll
                for (int j = 0; j < 8; ++j) { bfhl tt = hilo(u[j]); Ah[j] = tt.h; Al[j] = tt.l; }
            } else if (ks < 4) {   // XG k 32..63 = y1, from y1f frags
                Ah = *(const bf16x8*)(y1f + (((size_t)gnt * 2 + (ks - 2)) * 2 + 0) * 512 + l * 8);
                Al = *(const bf16x8*)(y1f + (((size_t)gnt * 2 + (ks - 2)) * 2 + 1) * 512 + l * 8);
            } else {               // XG k 64..95 = 2*y2-x, from xg2 LDS
                const int base = (t * 32 + o) * 36 + (ks - 4) * 16 + 8 * h;
                bf16x4 a0 = *(const bf16x4*)(xg2 + base);
                bf16x4 a1 = *(const bf16x4*)(xg2 + base + 4);
                bf16x4 b0 = *(const bf16x4*)(xg2 + 2304 + base);
                bf16x4 b1 = *(const bf16x4*)(xg2 + 2304 + base + 4);
                #pragma unroll
                for (int j = 0; j < 4; ++j) {
                    Ah[j] = a0[j]; Ah[4 + j] = a1[j];
                    Al[j] = b0[j]; Al[4 + j] = b1[j];
                }
            }
            #pragma unroll
            for (int ei = 0; ei < 4; ++ei) {
                bf16x8 Bh = *(const bf16x8*)(wq + (size_t)((e0 + ei) * 6 + ks) * 512 + o * 16 + h * 8);
                acc2[ei] = __builtin_amdgcn_mfma_f32_32x32x16_bf16(Ah, Bh, acc2[ei], 0, 0, 0);
                acc2[ei] = __builtin_amdgcn_mfma_f32_32x32x16_bf16(Al, Bh, acc2[ei], 0, 0, 0);
            }
        }

        float pr[16];
        #pragma unroll
        for (int r = 0; r < 16; ++r) pr[r] = 0.f;
        #pragma unroll
        for (int ei = 0; ei < 4; ++ei) {
            const int eg = e0 + ei;
            const float bv = bias[eg * 32 + o];
            #pragma unroll
            for (int r = 0; r < 16; ++r) {
                int nl = (r & 3) + 8 * (r >> 2) + 4 * h;
                pr[r] += s_s[(t * 32 + nl) * 16 + eg] * (acc2[ei][r] + bv);
            }
        }
        #pragma unroll
        for (int r = 0; r < 16; ++r) {
            int nl = (r & 3) + 8 * (r >> 2) + 4 * h;
            ps[w * 1056 + nl * 33 + o] = pr[r];
        }
        __syncthreads();
        {
            const int node = tid >> 3, og = (tid & 7) * 4;
            const int tt = node >> 5;
            float4 s;
            #pragma unroll
            for (int i = 0; i < 4; ++i) {
                int c = (node & 31) * 33 + og + i;
                ((float*)&s)[i] = ps[(tt * 4 + 0) * 1056 + c] + ps[(tt * 4 + 1) * 1056 + c] +
                                  ps[(tt * 4 + 2) * 1056 + c] + ps[(tt * 4 + 3) * 1056 + c];
            }
            *(float4*)(out + (size_t)(b * kN + q0 + node) * 32 + og) = s;
        }
    }
}

extern "C" void kernel_launch(void* const* d_in, const int* in_sizes, int n_in,
                              void* d_out, int out_size, void* d_ws, size_t ws_size,
                              hipStream_t stream) {
    const float* x     = (const float*)d_in[0];
    const float* aemb  = (const float*)d_in[1];
    const float* stock = (const float*)d_in[2];
    const float* Wp    = (const float*)d_in[3];
    const float* bias  = (const float*)d_in[4];
    float* out = (float*)d_out;

    __bf16* wsb  = (__bf16*)d_ws;
    __bf16* esf  = wsb;               // 524288 bf16
    __bf16* esq  = wsb + 524288;      // 524288 bf16
    __bf16* vtf1 = wsb + 1048576;     // 524288 bf16
    __bf16* vtf2 = wsb + 1572864;     // 524288 bf16
    __bf16* y1f  = wsb + 2097152;     // 1048576 bf16
    __bf16* wq   = wsb + 3145728;     // 49152 bf16

    prep<<<dim3(536), dim3(256), 0, stream>>>(aemb, x, Wp, esf, esq, vtf1, wq);
    apply_mfma<1><<<dim3(256), dim3(512), 0, stream>>>(
        esf, esq, vtf1, x, vtf2, y1f, wq, stock, bias, out);
    apply_mfma<2><<<dim3(256), dim3(512), 0, stream>>>(
        esf, esq, vtf2, x, nullptr, y1f, wq, stock, bias, out);
}

// Round 10
// 28.954 us; speedup vs baseline: 4.7568x; 1.0796x over previous
//
#include <hip/hip_runtime.h>
#include <stdint.h>

typedef __bf16 bf16x8 __attribute__((ext_vector_type(8)));
typedef __bf16 bf16x4 __attribute__((ext_vector_type(4)));
typedef float  f32x16 __attribute__((ext_vector_type(16)));

constexpr int kB = 16;
constexpr int kN = 1024;
constexpr float kLog2e = 1.44269504088896340736f;

struct bfhl { __bf16 h, l; };
__device__ __forceinline__ bfhl hilo(float v) {
    bfhl r;
    r.h = (__bf16)v;
    r.l = (__bf16)(v - (float)r.h);
    return r;
}

// m-offset ordering of P fragments: P0[j] holds row (j<4 ? j+4h : j+4+4h),
// P1 the same +16. V fragments are written in the identical order.
__device__ __forceinline__ int moff(int f, int h, int j) {
    return 16 * f + ((j < 4) ? (4 * h + j) : (4 * h + j + 4));
}

// ---------------------------------------------------------------------------
// Fragment layouts (bf16, lane = h*32 + (l&31), 8 elems = 16B/lane):
//  esf [b][kt(32)][pl(2)][lane][8] : E_pl[kt*32+(l&31)][8h+j]
//  esq same but E scaled by log2e (Q-side operand; exp2 domain)
//  vtf [b][mt(32)][f(2)][lane][8]  : V[d=(l&31)][mt*32+moff(f,h,j)]
//  y1f [gnt(512)][ks(2)][pl(2)][lane][8] : y1_pl[node=(l&31)][16ks+8h+j]
//  wq  [e][ks(6)][o*16+h*8+j]      : W_hi[16ks+8h+j][o]
// ---------------------------------------------------------------------------

__global__ __launch_bounds__(256) void prep(
    const float* __restrict__ emb, const float* __restrict__ x,
    const float* __restrict__ Wp,
    __bf16* __restrict__ esf, __bf16* __restrict__ esq,
    __bf16* __restrict__ vtf1, __bf16* __restrict__ wq)
{
    __shared__ float ls[64 * 36];
    const int tid = threadIdx.x;
    const int bid = blockIdx.x;

    if (bid < 256) {
        // emb -> esf + esq fragments. block = batch b, 64 rows.
        const int b = bid >> 4, rg = (bid & 15) << 6;
        const int r = tid >> 2, seg = tid & 3;
        float4 v = *(const float4*)(emb + ((size_t)(b * kN + rg + r) * 16 + seg * 4));
        float f[4] = {v.x, v.y, v.z, v.w};
        bf16x4 hi, lo, qhi, qlo;
        #pragma unroll
        for (int i = 0; i < 4; ++i) {
            bfhl t = hilo(f[i]);           hi[i] = t.h;  lo[i] = t.l;
            bfhl s = hilo(f[i] * kLog2e);  qhi[i] = s.h; qlo[i] = s.l;
        }
        const int kt = ((bid & 15) << 1) + (r >> 5);
        const int lane = ((seg >> 1) << 5) + (r & 31);
        const int j0 = (seg & 1) << 2;
        const size_t off = ((size_t)(b * 32 + kt) * 2) * 512 + lane * 8 + j0;
        *(bf16x4*)(esf + off)       = hi;
        *(bf16x4*)(esf + off + 512) = lo;
        *(bf16x4*)(esq + off)       = qhi;
        *(bf16x4*)(esq + off + 512) = qlo;
    } else if (bid < 512) {
        // x -> vtf1 fragments. block = batch b, 64 rows (2 m-tiles).
        const int bb = bid - 256;
        const int b = bb >> 4, n0 = (bb & 15) << 6;
        const float* sB = x + ((size_t)b * kN + n0) * 32;
        #pragma unroll
        for (int it = 0; it < 2; ++it) {
            int f = it * 256 + tid;
            int row = f >> 3, q8 = f & 7;
            float4 v = *(const float4*)(sB + (size_t)row * 32 + q8 * 4);
            *(float4*)(&ls[row * 36 + q8 * 4]) = v;
        }
        __syncthreads();
        {
            const int mt = tid >> 7, fr = (tid >> 6) & 1, l = tid & 63;
            const int d = l & 31, h = l >> 5;
            bf16x8 ov;
            #pragma unroll
            for (int j = 0; j < 8; ++j)
                ov[j] = (__bf16)ls[(mt * 32 + moff(fr, h, j)) * 36 + d];
            *(bf16x8*)(vtf1 + ((size_t)(b * 32 + (n0 >> 5) + mt) * 2 + fr) * 512 + l * 8) = ov;
        }
    } else {
        int idx = (bid - 512) * 256 + tid;   // (e, ks, o, h)
        if (idx < 6144) {
            int e = idx / 384, rem = idx - e * 384;
            int ks = rem / 64, r2 = rem - ks * 64;
            int o = r2 >> 1, hh = r2 & 1;
            int ki0 = ks * 16 + hh * 8;
            bf16x8 hi;
            #pragma unroll
            for (int j = 0; j < 8; ++j)
                hi[j] = (__bf16)Wp[(size_t)e * 3072 + (size_t)(ki0 + j) * 32 + o];
            *(bf16x8*)(wq + (size_t)(e * 6 + ks) * 512 + o * 16 + hh * 8) = hi;
        }
    }
}

// ---------------------------------------------------------------------------
// apply_mfma<STAGE>: softmax_row(relu(E E^T)) @ V via bf16 MFMA 32x32x16.
// grid 512 (XCD-swizzled), 256 threads (4 waves). Wave w: kt = w*8 + it*2+{0,1}
// -> two independent S-chains per iter (ILP) + next-iter loads prefetched.
// STAGE 1: V=vtf1(x); epilogue -> vtf2 frags + y1f frags.
// STAGE 2: V=vtf2(y1); epilogue = fused final GEMM -> out.
// ---------------------------------------------------------------------------
template<int STAGE>
__global__ __launch_bounds__(256, 2) void apply_mfma(
    const __bf16* __restrict__ esf, const __bf16* __restrict__ esq,
    const __bf16* __restrict__ vtin,
    const float*  __restrict__ x,
    __bf16* __restrict__ vtout, __bf16* __restrict__ y1f,
    const __bf16* __restrict__ wq,
    const float*  __restrict__ stock, const float* __restrict__ bias,
    float* __restrict__ out)
{
    __shared__ alignas(16) char smem[28672];
    float*  ps  = (float*)smem;             // 4224 f32
    float*  Ls  = (float*)(smem + 16896);   // 128 f32
    float*  yb  = (float*)(smem + 17408);   // 32*36 f32
    __bf16* xg2 = (__bf16*)(smem + 22016);  // [2][32][36] bf16 (stage2)
    float*  s_s = (float*)(smem + 26624);   // 32*16 f32 (stage2)

    const int tid = threadIdx.x;
    const int w = tid >> 6, l = tid & 63;
    const int q = l & 31, h = l >> 5;
    const int bs = ((blockIdx.x & 7) << 6) | (blockIdx.x >> 3);   // XCD swizzle
    const int b = bs >> 5, nt = bs & 31, q0 = nt << 5;
    const int gnt = b * 32 + nt;

    const __bf16* esfB = esf + (size_t)b * 32768;
    const __bf16* esqB = esq + (size_t)b * 32768;
    const __bf16* vtfB = vtin + (size_t)b * 32768;

    if (STAGE == 2) {   // stage stock (read after merge sync)
        int r = tid >> 3, e2 = (tid & 7) * 2;
        *(float2*)(s_s + r * 16 + e2) =
            *(const float2*)(stock + (size_t)(b * kN + q0 + r) * 16 + e2);
    }

    // Q-side B-fragments (log2e-scaled)
    bf16x8 bhi = *(const bf16x8*)(esqB + ((size_t)nt * 2) * 512 + l * 8);
    bf16x8 blo = *(const bf16x8*)(esqB + ((size_t)nt * 2 + 1) * 512 + l * 8);

    f32x16 acc = {};
    float Lp = 0.f;

#define LOADK(kt, ahi, alo, V0, V1) \
    ahi = *(const bf16x8*)(esfB + ((size_t)(kt) * 2) * 512 + l * 8);     \
    alo = *(const bf16x8*)(esfB + ((size_t)(kt) * 2 + 1) * 512 + l * 8); \
    V0  = *(const bf16x8*)(vtfB + ((size_t)(kt) * 2) * 512 + l * 8);     \
    V1  = *(const bf16x8*)(vtfB + ((size_t)(kt) * 2 + 1) * 512 + l * 8);

    const int ktb = w * 8;
    bf16x8 cahiA, caloA, cV0A, cV1A, cahiB, caloB, cV0B, cV1B;
    LOADK(ktb + 0, cahiA, caloA, cV0A, cV1A);
    LOADK(ktb + 1, cahiB, caloB, cV0B, cV1B);

    #pragma unroll
    for (int it = 0; it < 4; ++it) {
        bf16x8 nahiA, naloA, nV0A, nV1A, nahiB, naloB, nV0B, nV1B;
        if (it < 3) {
            LOADK(ktb + it * 2 + 2, nahiA, naloA, nV0A, nV1A);
            LOADK(ktb + it * 2 + 3, nahiB, naloB, nV0B, nV1B);
        }
        f32x16 S0 = {}, S1 = {};
        S0 = __builtin_amdgcn_mfma_f32_32x32x16_bf16(cahiA, bhi, S0, 0, 0, 0);
        S1 = __builtin_amdgcn_mfma_f32_32x32x16_bf16(cahiB, bhi, S1, 0, 0, 0);
        S0 = __builtin_amdgcn_mfma_f32_32x32x16_bf16(cahiA, blo, S0, 0, 0, 0);
        S1 = __builtin_amdgcn_mfma_f32_32x32x16_bf16(cahiB, blo, S1, 0, 0, 0);
        S0 = __builtin_amdgcn_mfma_f32_32x32x16_bf16(caloA, bhi, S0, 0, 0, 0);
        S1 = __builtin_amdgcn_mfma_f32_32x32x16_bf16(caloB, bhi, S1, 0, 0, 0);

        float p0[16], p1[16];
        #pragma unroll
        for (int r = 0; r < 16; ++r) {
            p0[r] = exp2f(fmaxf(S0[r], 0.f));  Lp += p0[r];
            p1[r] = exp2f(fmaxf(S1[r], 0.f));  Lp += p1[r];
        }
        bf16x8 P00, P01, P10, P11;
        #pragma unroll
        for (int j = 0; j < 8; ++j) {
            P00[j] = (__bf16)p0[j]; P01[j] = (__bf16)p0[8 + j];
            P10[j] = (__bf16)p1[j]; P11[j] = (__bf16)p1[8 + j];
        }
        acc = __builtin_amdgcn_mfma_f32_32x32x16_bf16(cV0A, P00, acc, 0, 0, 0);
        acc = __builtin_amdgcn_mfma_f32_32x32x16_bf16(cV1A, P01, acc, 0, 0, 0);
        acc = __builtin_amdgcn_mfma_f32_32x32x16_bf16(cV0B, P10, acc, 0, 0, 0);
        acc = __builtin_amdgcn_mfma_f32_32x32x16_bf16(cV1B, P11, acc, 0, 0, 0);

        cahiA = nahiA; caloA = naloA; cV0A = nV0A; cV1A = nV1A;
        cahiB = nahiB; caloB = naloB; cV0B = nV0B; cV1B = nV1B;
    }
#undef LOADK

    // ---- merge 4 wave-partials ----
    Lp += __shfl_xor(Lp, 32);
    #pragma unroll
    for (int r = 0; r < 16; ++r) {
        int d = (r & 3) + 8 * (r >> 2) + 4 * h;
        ps[w * 1056 + d * 33 + q] = acc[r];
    }
    if (l < 32) Ls[w * 32 + l] = Lp;
    __syncthreads();

    const int qq = tid >> 3, dg = tid & 7;
    const float iL = 1.f / (Ls[qq] + Ls[32 + qq] + Ls[64 + qq] + Ls[96 + qq]);
    float yv[4];
    #pragma unroll
    for (int i = 0; i < 4; ++i) {
        int d = dg * 4 + i;
        yv[i] = (ps[d * 33 + qq] + ps[1056 + d * 33 + qq] +
                 ps[2112 + d * 33 + qq] + ps[3168 + d * 33 + qq]) * iL;
    }

    if (STAGE == 1) {
        #pragma unroll
        for (int i = 0; i < 4; ++i) yb[qq * 36 + dg * 4 + i] = yv[i];
        __syncthreads();
        if (tid < 128) {   // vtf2 fragments
            int fr = tid >> 6, l2 = tid & 63;
            int d = l2 & 31, h2 = l2 >> 5;
            bf16x8 ov;
            #pragma unroll
            for (int j = 0; j < 8; ++j)
                ov[j] = (__bf16)yb[moff(fr, h2, j) * 36 + d];
            *(bf16x8*)(vtout + ((size_t)gnt * 2 + fr) * 512 + l2 * 8) = ov;
        }
        {   // y1f fragments
            int ks2 = tid >> 7, pl = (tid >> 6) & 1, l2 = tid & 63;
            int node = l2 & 31, h2 = l2 >> 5;
            const float* rp = yb + node * 36 + ks2 * 16 + 8 * h2;
            bf16x8 ov;
            #pragma unroll
            for (int j = 0; j < 8; ++j) {
                bfhl tt = hilo(rp[j]);
                ov[j] = pl ? tt.l : tt.h;
            }
            *(bf16x8*)(y1f + (((size_t)gnt * 2 + ks2) * 2 + pl) * 512 + l2 * 8) = ov;
        }
    } else {
        // ---- fused final: xg2 = 2*y2 - x (k 64..95), then out ----
        {
            float4 xv = *(const float4*)(x + (size_t)(b * kN + q0 + qq) * 32 + dg * 4);
            float xa[4] = {xv.x, xv.y, xv.z, xv.w};
            bf16x4 hi, lo;
            #pragma unroll
            for (int i = 0; i < 4; ++i) {
                bfhl tt = hilo(2.f * yv[i] - xa[i]);
                hi[i] = tt.h; lo[i] = tt.l;
            }
            *(bf16x4*)(xg2 + qq * 36 + dg * 4)        = hi;
            *(bf16x4*)(xg2 + 1152 + qq * 36 + dg * 4) = lo;
        }
        __syncthreads();

        f32x16 acc2[4] = {};
        const int e0 = w * 4;
        const int o = q;   // A-side node index == B/D-side o index

        #pragma unroll
        for (int ks = 0; ks < 6; ++ks) {
            bf16x8 Ah, Al;
            if (ks < 2) {          // XG k 0..31 = x, from global
                const float* rp = x + (size_t)(b * kN + q0 + q) * 32 + ks * 16 + 8 * h;
                float4 u0 = *(const float4*)rp;
                float4 u1 = *(const float4*)(rp + 4);
                float u[8] = {u0.x, u0.y, u0.z, u0.w, u1.x, u1.y, u1.z, u1.w};
                #pragma unroll
                for (int j = 0; j < 8; ++j) { bfhl tt = hilo(u[j]); Ah[j] = tt.h; Al[j] = tt.l; }
            } else if (ks < 4) {   // XG k 32..63 = y1, from y1f frags
                Ah = *(const bf16x8*)(y1f + (((size_t)gnt * 2 + (ks - 2)) * 2 + 0) * 512 + l * 8);
                Al = *(const bf16x8*)(y1f + (((size_t)gnt * 2 + (ks - 2)) * 2 + 1) * 512 + l * 8);
            } else {               // XG k 64..95 = 2*y2-x, from xg2 LDS
                const int base = o * 36 + (ks - 4) * 16 + 8 * h;
                bf16x4 a0 = *(const bf16x4*)(xg2 + base);
                bf16x4 a1 = *(const bf16x4*)(xg2 + base + 4);
                bf16x4 b0 = *(const bf16x4*)(xg2 + 1152 + base);
                bf16x4 b1 = *(const bf16x4*)(xg2 + 1152 + base + 4);
                #pragma unroll
                for (int j = 0; j < 4; ++j) {
                    Ah[j] = a0[j]; Ah[4 + j] = a1[j];
                    Al[j] = b0[j]; Al[4 + j] = b1[j];
                }
            }
            #pragma unroll
            for (int ei = 0; ei < 4; ++ei) {
                bf16x8 Bh = *(const bf16x8*)(wq + (size_t)((e0 + ei) * 6 + ks) * 512 + o * 16 + h * 8);
                acc2[ei] = __builtin_amdgcn_mfma_f32_32x32x16_bf16(Ah, Bh, acc2[ei], 0, 0, 0);
                acc2[ei] = __builtin_amdgcn_mfma_f32_32x32x16_bf16(Al, Bh, acc2[ei], 0, 0, 0);
            }
        }

        float pr[16];
        #pragma unroll
        for (int r = 0; r < 16; ++r) pr[r] = 0.f;
        #pragma unroll
        for (int ei = 0; ei < 4; ++ei) {
            const int eg = e0 + ei;
            const float bv = bias[eg * 32 + o];
            #pragma unroll
            for (int r = 0; r < 16; ++r) {
                int node = (r & 3) + 8 * (r >> 2) + 4 * h;
                pr[r] += s_s[node * 16 + eg] * (acc2[ei][r] + bv);
            }
        }
        #pragma unroll
        for (int r = 0; r < 16; ++r) {
            int node = (r & 3) + 8 * (r >> 2) + 4 * h;
            ps[w * 1056 + node * 33 + o] = pr[r];
        }
        __syncthreads();
        {
            const int node = tid >> 3, og = (tid & 7) * 4;
            float4 s;
            #pragma unroll
            for (int i = 0; i < 4; ++i) {
                int c = node * 33 + og + i;
                ((float*)&s)[i] = ps[c] + ps[1056 + c] + ps[2112 + c] + ps[3168 + c];
            }
            *(float4*)(out + (size_t)(b * kN + q0 + node) * 32 + og) = s;
        }
    }
}

extern "C" void kernel_launch(void* const* d_in, const int* in_sizes, int n_in,
                              void* d_out, int out_size, void* d_ws, size_t ws_size,
                              hipStream_t stream) {
    const float* x     = (const float*)d_in[0];
    const float* aemb  = (const float*)d_in[1];
    const float* stock = (const float*)d_in[2];
    const float* Wp    = (const float*)d_in[3];
    const float* bias  = (const float*)d_in[4];
    float* out = (float*)d_out;

    __bf16* wsb  = (__bf16*)d_ws;
    __bf16* esf  = wsb;               // 524288 bf16
    __bf16* esq  = wsb + 524288;      // 524288 bf16
    __bf16* vtf1 = wsb + 1048576;     // 524288 bf16
    __bf16* vtf2 = wsb + 1572864;     // 524288 bf16
    __bf16* y1f  = wsb + 2097152;     // 1048576 bf16
    __bf16* wq   = wsb + 3145728;     // 49152 bf16

    prep<<<dim3(536), dim3(256), 0, stream>>>(aemb, x, Wp, esf, esq, vtf1, wq);
    apply_mfma<1><<<dim3(512), dim3(256), 0, stream>>>(
        esf, esq, vtf1, x, vtf2, y1f, wq, stock, bias, out);
    apply_mfma<2><<<dim3(512), dim3(256), 0, stream>>>(
        esf, esq, vtf2, x, nullptr, y1f, wq, stock, bias, out);
}